// Round 12
// baseline (293.355 us; speedup 1.0000x reference)
//
#include <hip/hip_runtime.h>

#define N_NODES 50000
#define N_EDGES 800000
#define C_IN 128
#define C_OUT 256
#define BN_EPS 1e-5f
#define NBLK ((N_NODES + 255) / 256)   // 196 scan blocks
#define SL 8                           // channel slices (== XCD count)
#define SLC 32                         // channels per slice
#define NPB 128                        // nodes per gather block (8 per 16-lane group)
#define PAD 8                          // LDS row pad (elems, keeps 16B align)
#define TSW 132                        // transpose LDS row stride (shorts)

#define HB 782                         // hist/scatter blocks (1024 edges each)
#define GBX ((N_NODES + 127) / 128)    // 391 gemm row-tiles
#define GB (GBX * 4)                   // 1564 gemm blocks

using short8  = __attribute__((ext_vector_type(8))) short;
using floatx4 = __attribute__((ext_vector_type(4))) float;
using h2      = __attribute__((ext_vector_type(2))) _Float16;

union UH2 { unsigned int u; h2 h; };
union HS  { _Float16 f; unsigned short s; };

// packed f16 max -> v_pk_max_f16 (no header dependency; ROCm 7.2 lacks __hmax2)
__device__ __forceinline__ h2 pkmax(h2 a, h2 b) {
    return __builtin_elementwise_max(a, b);
}

// fp32 -> bf16 round-to-nearest-even (GEMM inputs only)
__device__ __forceinline__ unsigned short f2bf(float f) {
    unsigned int u = __float_as_uint(f);
    u = (u + 0x7fffu + ((u >> 16) & 1u)) >> 16;
    return (unsigned short)u;
}

#define XQ (N_NODES * C_IN / 4)        // 1,600,000 float4 of x
#define WQ (512 * C_IN / 4)            // 16,384 float4 of W'

// ---------------------------------------------------------------------------
// prep: fused [src-degree histogram] + [convert x->bf16, W'->bf16].
// Identity: theta@(xj-xi) + phi@xi = u[dst] + v[src]; relu/max commute so
// the edge pass only needs max over u rows.
// ---------------------------------------------------------------------------
__global__ __launch_bounds__(256) void prep(
    const float* __restrict__ x, const float* __restrict__ theta,
    const float* __restrict__ phi, const int* __restrict__ src,
    unsigned short* __restrict__ xb, unsigned short* __restrict__ wb,
    int* __restrict__ deg)
{
    const int tid = threadIdx.x;
    if (blockIdx.x < HB) {
        const int base = blockIdx.x * 1024 + tid;
        #pragma unroll
        for (int k = 0; k < 4; ++k) {
            int e = base + k * 256;
            if (e < N_EDGES) atomicAdd(&deg[src[e]], 1);
        }
        return;
    }
    int i = (blockIdx.x - HB) * 256 + tid;
    if (i < XQ) {
        float4 vv = ((const float4*)x)[i];
        ((ushort4*)xb)[i] = make_ushort4(f2bf(vv.x), f2bf(vv.y),
                                         f2bf(vv.z), f2bf(vv.w));
    } else if (i < XQ + WQ) {
        int j = i - XQ;
        float4 t;
        if (j < 256 * C_IN / 4) {
            t = ((const float4*)theta)[j];
        } else {
            int k = j - 256 * C_IN / 4;
            float4 th = ((const float4*)theta)[k];
            float4 ph = ((const float4*)phi)[k];
            t = make_float4(ph.x - th.x, ph.y - th.y, ph.z - th.z, ph.w - th.w);
        }
        ((ushort4*)wb)[j] = make_ushort4(f2bf(t.x), f2bf(t.y),
                                         f2bf(t.z), f2bf(t.w));
    }
}

// ---------------------------------------------------------------------------
// CSR scan: per-block partials, then scan_fin with the 196-entry mid-scan
// done redundantly per block in LDS.
// ---------------------------------------------------------------------------
__global__ __launch_bounds__(256) void scan_part(
    const int* __restrict__ deg, int* __restrict__ partials)
{
    __shared__ int s[256];
    const int tid = threadIdx.x;
    int i = blockIdx.x * 256 + tid;
    s[tid] = (i < N_NODES) ? deg[i] : 0;
    __syncthreads();
    for (int d = 128; d > 0; d >>= 1) {
        if (tid < d) s[tid] += s[tid + d];
        __syncthreads();
    }
    if (tid == 0) partials[blockIdx.x] = s[0];
}

__global__ __launch_bounds__(256) void scan_fin(
    const int* __restrict__ deg, const int* __restrict__ partials,
    int* __restrict__ off, int* __restrict__ cursor)
{
    __shared__ int s[256];
    const int tid = threadIdx.x;

    int pv = (tid < NBLK) ? partials[tid] : 0;
    s[tid] = pv;
    __syncthreads();
    for (int d = 1; d < 256; d <<= 1) {
        int t = (tid >= d) ? s[tid - d] : 0;
        __syncthreads();
        s[tid] += t;
        __syncthreads();
    }
    const int blockPrefix = (blockIdx.x == 0) ? 0 : s[blockIdx.x - 1];
    const int total = s[NBLK - 1];
    __syncthreads();

    int i = blockIdx.x * 256 + tid;
    int v = (i < N_NODES) ? deg[i] : 0;
    s[tid] = v;
    __syncthreads();
    for (int d = 1; d < 256; d <<= 1) {
        int t = (tid >= d) ? s[tid - d] : 0;
        __syncthreads();
        s[tid] += t;
        __syncthreads();
    }
    int ex = s[tid] - v + blockPrefix;
    if (i < N_NODES) { off[i] = ex; cursor[i] = ex; }
    if (blockIdx.x == 0 && tid == 0) off[N_NODES] = total;
}

// ---------------------------------------------------------------------------
// gemm_scatter v3: fused [edge bucket-scatter] + [MFMA GEMM].
// R11 lesson: the epilogue's 64 scalar 2B stores/lane (4x 32B segments per
// wave-store) were the serializer — WRITE_SIZE 104 MB = 2x payload.
// Fix: LDS-transpose epilogue. After the MFMA loop, barrier, reuse the Bs
// LDS as a per-wave 32x132-short scratch: 64 ds_write_b16/lane, then each
// lane stores one full 64B u/v row-slice as 4 contiguous dwordx4 — 8 wide
// stores/lane, every store a full aligned line.
// Verified layouts: A-frag A[m=lane&15][k=quad*8+j]; B-frag B[k][n=lane&15];
// C/D col=lane&15, row=quad*4+reg (learn_hip m89/m91).
// ---------------------------------------------------------------------------
__global__ __launch_bounds__(256) void gemm_scatter(
    const unsigned short* __restrict__ xb,   // [N,128] bf16
    const unsigned short* __restrict__ wb,   // [512,128] bf16
    unsigned short* __restrict__ u,          // [SL][N][SLC] fp16
    unsigned short* __restrict__ v,          // [SL][N][SLC] fp16
    const int* __restrict__ src, const int* __restrict__ dst,
    int* __restrict__ cursor, int* __restrict__ edst)
{
    __shared__ unsigned short Bs[128][C_IN + PAD];   // 34816 B; reused for transpose
    const int tid = threadIdx.x;

    if (blockIdx.x < HB) {
        const int base = blockIdx.x * 1024 + tid;
        int e0 = base, e1 = base + 256, e2 = base + 512, e3 = base + 768;
        int s0 = (e0 < N_EDGES) ? src[e0] : -1;
        int s1 = (e1 < N_EDGES) ? src[e1] : -1;
        int s2 = (e2 < N_EDGES) ? src[e2] : -1;
        int s3 = (e3 < N_EDGES) ? src[e3] : -1;
        int d0 = (e0 < N_EDGES) ? dst[e0] : 0;
        int d1 = (e1 < N_EDGES) ? dst[e1] : 0;
        int d2 = (e2 < N_EDGES) ? dst[e2] : 0;
        int d3 = (e3 < N_EDGES) ? dst[e3] : 0;
        if (s0 >= 0) edst[atomicAdd(&cursor[s0], 1)] = d0;
        if (s1 >= 0) edst[atomicAdd(&cursor[s1], 1)] = d1;
        if (s2 >= 0) edst[atomicAdd(&cursor[s2], 1)] = d2;
        if (s3 >= 0) edst[atomicAdd(&cursor[s3], 1)] = d3;
        return;
    }

    const int b = blockIdx.x - HB;
    const int bx = b >> 2;
    const int by = b & 3;
    const int wave = tid >> 6;
    const int lane = tid & 63;
    const int l15 = lane & 15;
    const int quad = lane >> 4;

    // Stage B: 128 rows x 128 bf16 (2 threads/row, 8 uint4 each).
    {
        int r = tid >> 1;
        int cb = (tid & 1) * 64;
        const uint4* sp = (const uint4*)(wb + (size_t)(by * 128 + r) * C_IN + cb);
        #pragma unroll
        for (int i = 0; i < 8; ++i) *(uint4*)&Bs[r][cb + i * 8] = sp[i];
    }

    // A fragment base pointers (rows clamped; OOB rows never stored).
    const int n0 = bx * 128 + wave * 32 + l15;
    const unsigned short* arow0 = xb + (size_t)min(n0,      N_NODES - 1) * C_IN + quad * 8;
    const unsigned short* arow1 = xb + (size_t)min(n0 + 16, N_NODES - 1) * C_IN + quad * 8;

    __syncthreads();

    floatx4 acc[2][8];
    #pragma unroll
    for (int mi = 0; mi < 2; ++mi)
        #pragma unroll
        for (int ni = 0; ni < 8; ++ni)
            acc[mi][ni] = (floatx4){0.f, 0.f, 0.f, 0.f};

    #pragma unroll
    for (int ks = 0; ks < 4; ++ks) {
        short8 a[2], bfr[8];
        a[0] = *(const short8*)(arow0 + ks * 32);
        a[1] = *(const short8*)(arow1 + ks * 32);
        #pragma unroll
        for (int ni = 0; ni < 8; ++ni)
            bfr[ni] = *(const short8*)&Bs[ni * 16 + l15][ks * 32 + quad * 8];
        #pragma unroll
        for (int mi = 0; mi < 2; ++mi)
            #pragma unroll
            for (int ni = 0; ni < 8; ++ni)
                acc[mi][ni] = __builtin_amdgcn_mfma_f32_16x16x32_bf16(
                    a[mi], bfr[ni], acc[mi][ni], 0, 0, 0);
    }

    // ---- LDS-transpose epilogue ----
    __syncthreads();   // all waves done reading Bs; reuse its storage.
    unsigned short* tr = &Bs[0][0] + wave * 32 * TSW;   // wave-private 32x132

    #pragma unroll
    for (int mi = 0; mi < 2; ++mi)
        #pragma unroll
        for (int r = 0; r < 4; ++r) {
            const int lrow = mi * 16 + quad * 4 + r;
            #pragma unroll
            for (int ni = 0; ni < 8; ++ni) {
                HS hv; hv.f = (_Float16)acc[mi][ni][r];
                tr[lrow * TSW + ni * 16 + l15] = hv.s;
            }
        }
    // Wave-private region: no barrier needed (lgkmcnt ordering within wave).

    unsigned short* base_uv = (by < 2) ? u : v;
    const int sb = (by & 1) * 4;
    #pragma unroll
    for (int p = 0; p < 2; ++p) {
        const int seg = p * 64 + lane;        // 0..127
        const int row = seg & 31;
        const int cblk = seg >> 5;            // 0..3
        const int n = bx * 128 + wave * 32 + row;
        if (n < N_NODES) {
            const unsigned short* lsrc = tr + row * TSW + cblk * 32;
            uint4 q0 = *(const uint4*)(lsrc + 0);
            uint4 q1 = *(const uint4*)(lsrc + 8);
            uint4 q2 = *(const uint4*)(lsrc + 16);
            uint4 q3 = *(const uint4*)(lsrc + 24);
            uint4* dp = (uint4*)(base_uv + ((size_t)(sb + cblk) * N_NODES + n) * SLC);
            dp[0] = q0; dp[1] = q1; dp[2] = q2; dp[3] = q3;
        }
    }
}

// ---------------------------------------------------------------------------
// Sliced gather-max. blockIdx & 7 = channel slice = XCD: XCD s only touches
// u-slice s (3.2 MB, its-L2-resident). One node per 16-lane group, 8-deep
// edge unroll. pkmax -> native v_pk_max_f16 (bf16 __hmax2 is emulated, R6).
// ---------------------------------------------------------------------------
__global__ __launch_bounds__(256) void gather_slice(
    const int* __restrict__ off, const int* __restrict__ edst,
    const unsigned short* __restrict__ u, const unsigned short* __restrict__ v,
    float* __restrict__ out, float* __restrict__ sums, float* __restrict__ sumsq)
{
    const int slice = blockIdx.x & 7;
    const int chunk = blockIdx.x >> 3;
    const int wave = threadIdx.x >> 6;
    const int lane = threadIdx.x & 63;
    const int grp = lane >> 4;        // node sub-group 0..3
    const int l16 = lane & 15;        // channel-pair index within slice
    const int loff = l16 * 4;         // byte offset within 64B u row
    const int g16 = wave * 4 + grp;   // block-level group id 0..15

    const char* ub = (const char*)(u + (size_t)slice * N_NODES * SLC);
    const unsigned short* vb = v + (size_t)slice * N_NODES * SLC;

    float s1_0 = 0.f, s1_1 = 0.f, s2_0 = 0.f, s2_1 = 0.f;

    #pragma unroll 1
    for (int i = 0; i < NPB / 16; ++i) {
        const int n = chunk * NPB + i * 16 + g16;
        if (n >= N_NODES) continue;
        const int start = off[n];
        const int end = off[n + 1];
        float a0 = 0.f, a1 = 0.f;
        if (end > start) {
            UH2 m; m.u = 0xFC00FC00u;           // packed f16 -inf
            const int nfull = (end - start) >> 3;
            const int* ep = edst + start;
            for (int it = 0; it < nfull; ++it) {
                int d0 = ep[0], d1 = ep[1], d2 = ep[2], d3 = ep[3];
                int d4 = ep[4], d5 = ep[5], d6 = ep[6], d7 = ep[7];
                UH2 w0, w1, w2, w3, w4, w5, w6, w7;
                w0.u = *(const unsigned int*)(ub + ((d0 << 6) | loff));
                w1.u = *(const unsigned int*)(ub + ((d1 << 6) | loff));
                w2.u = *(const unsigned int*)(ub + ((d2 << 6) | loff));
                w3.u = *(const unsigned int*)(ub + ((d3 << 6) | loff));
                w4.u = *(const unsigned int*)(ub + ((d4 << 6) | loff));
                w5.u = *(const unsigned int*)(ub + ((d5 << 6) | loff));
                w6.u = *(const unsigned int*)(ub + ((d6 << 6) | loff));
                w7.u = *(const unsigned int*)(ub + ((d7 << 6) | loff));
                h2 t0 = pkmax(pkmax(w0.h, w1.h), pkmax(w2.h, w3.h));
                h2 t1 = pkmax(pkmax(w4.h, w5.h), pkmax(w6.h, w7.h));
                m.h = pkmax(m.h, pkmax(t0, t1));
                ep += 8;
            }
            const int base = start + (nfull << 3);
            if (base < end) {                 // clamped tail (dups ok under max)
                const int lim = end - 1;
                int d0 = edst[base];
                int d1 = edst[min(base + 1, lim)], d2 = edst[min(base + 2, lim)];
                int d3 = edst[min(base + 3, lim)], d4 = edst[min(base + 4, lim)];
                int d5 = edst[min(base + 5, lim)], d6 = edst[min(base + 6, lim)];
                int d7 = edst[min(base + 7, lim)];
                UH2 w0, w1, w2, w3, w4, w5, w6, w7;
                w0.u = *(const unsigned int*)(ub + ((d0 << 6) | loff));
                w1.u = *(const unsigned int*)(ub + ((d1 << 6) | loff));
                w2.u = *(const unsigned int*)(ub + ((d2 << 6) | loff));
                w3.u = *(const unsigned int*)(ub + ((d3 << 6) | loff));
                w4.u = *(const unsigned int*)(ub + ((d4 << 6) | loff));
                w5.u = *(const unsigned int*)(ub + ((d5 << 6) | loff));
                w6.u = *(const unsigned int*)(ub + ((d6 << 6) | loff));
                w7.u = *(const unsigned int*)(ub + ((d7 << 6) | loff));
                h2 t0 = pkmax(pkmax(w0.h, w1.h), pkmax(w2.h, w3.h));
                h2 t1 = pkmax(pkmax(w4.h, w5.h), pkmax(w6.h, w7.h));
                m.h = pkmax(m.h, pkmax(t0, t1));
            }
            UH2 wv; wv.u = *(const unsigned int*)(vb + (size_t)n * SLC + l16 * 2);
            a0 = fmaxf((float)wv.h[0] + (float)m.h[0], 0.f);
            a1 = fmaxf((float)wv.h[1] + (float)m.h[1], 0.f);
        }
        *(float2*)(out + (size_t)n * C_OUT + slice * SLC + l16 * 2) =
            make_float2(a0, a1);
        s1_0 += a0; s1_1 += a1;
        s2_0 += a0 * a0; s2_1 += a1 * a1;
    }

    // Stats: reduce across the 16 groups; channels are disjoint per l16.
    __shared__ float red[16][16][4];
    red[g16][l16][0] = s1_0; red[g16][l16][1] = s1_1;
    red[g16][l16][2] = s2_0; red[g16][l16][3] = s2_1;
    __syncthreads();
    if (threadIdx.x < 16) {
        const int t = threadIdx.x;
        float r0 = 0.f, r1 = 0.f, r2 = 0.f, r3 = 0.f;
        #pragma unroll
        for (int g = 0; g < 16; ++g) {
            r0 += red[g][t][0]; r1 += red[g][t][1];
            r2 += red[g][t][2]; r3 += red[g][t][3];
        }
        const int c = slice * SLC + t * 2;
        atomicAdd(&sums[c + 0], r0);
        atomicAdd(&sums[c + 1], r1);
        atomicAdd(&sumsq[c + 0], r2);
        atomicAdd(&sumsq[c + 1], r3);
    }
}

// ---------------------------------------------------------------------------
// BN + ReLU, coefs computed redundantly per block in LDS.
// ---------------------------------------------------------------------------
__global__ __launch_bounds__(256) void bn_apply(
    float* __restrict__ out, const float* __restrict__ sums,
    const float* __restrict__ sumsq, const float* __restrict__ gamma,
    const float* __restrict__ beta)
{
    __shared__ float cA[C_OUT], cB[C_OUT];
    const int tid = threadIdx.x;
    {
        const float inv_n = 1.f / (float)N_NODES;
        const float mean = sums[tid] * inv_n;
        const float var = sumsq[tid] * inv_n - mean * mean;
        const float s = rsqrtf(var + BN_EPS) * gamma[tid];
        cA[tid] = s;
        cB[tid] = beta[tid] - mean * s;
    }
    __syncthreads();

    const int c4 = (tid * 4) & (C_OUT - 1);
    const float4 A = *(const float4*)(cA + c4);
    const float4 B = *(const float4*)(cB + c4);
    const int base = blockIdx.x * 1024 + tid;
    #pragma unroll
    for (int k = 0; k < 4; ++k) {
        const int i = base + k * 256;
        float4 o = ((float4*)out)[i];
        o.x = fmaxf(o.x * A.x + B.x, 0.f);
        o.y = fmaxf(o.y * A.y + B.y, 0.f);
        o.z = fmaxf(o.z * A.z + B.z, 0.f);
        o.w = fmaxf(o.w * A.w + B.w, 0.f);
        ((float4*)out)[i] = o;
    }
}

extern "C" void kernel_launch(void* const* d_in, const int* in_sizes, int n_in,
                              void* d_out, int out_size, void* d_ws, size_t ws_size,
                              hipStream_t stream) {
    const float* x     = (const float*)d_in[0];
    const int*   src   = (const int*)d_in[1];
    const int*   dst   = (const int*)d_in[2];
    const float* theta = (const float*)d_in[3];
    const float* phi   = (const float*)d_in[4];
    const float* gamma = (const float*)d_in[5];
    const float* beta  = (const float*)d_in[6];
    float* out = (float*)d_out;

    // Workspace layout (16B-aligned chunks):
    char* ws = (char*)d_ws;
    const size_t uv_elems = (size_t)N_NODES * C_OUT;
    unsigned short* u = (unsigned short*)ws;                       // 25.6 MB fp16 slice-major
    unsigned short* v = u + uv_elems;                              // 25.6 MB fp16 slice-major
    float* sums   = (float*)(v + uv_elems);
    float* sumsq  = sums + C_OUT;
    int*   deg    = (int*)(sumsq + C_OUT);                         // contiguous for one memset
    int*   off    = deg + N_NODES;                                 // N_NODES+1 entries
    int*   cursor = off + N_NODES + 4;                             // pad keeps 16B align
    int*   edst   = cursor + N_NODES;                              // 3.2 MB
    int*   partials = edst + N_EDGES;                              // NBLK ints
    unsigned short* xb = (unsigned short*)(partials + NBLK + 8);   // 12.8 MB bf16
    unsigned short* wb = xb + (size_t)N_NODES * C_IN;              // 128 KB bf16

    // Zero sums/sumsq/deg in one shot (contiguous).
    hipMemsetAsync(sums, 0, (2 * C_OUT + N_NODES) * sizeof(int), stream);

    // Fused hist + convert.
    prep<<<HB + (XQ + WQ + 255) / 256, 256, 0, stream>>>(
        x, theta, phi, src, xb, wb, deg);

    scan_part<<<NBLK, 256, 0, stream>>>(deg, partials);
    scan_fin<<<NBLK, 256, 0, stream>>>(deg, partials, off, cursor);

    // Fused scatter + MFMA GEMM (A direct-from-global, B in LDS, transposed epilogue).
    gemm_scatter<<<HB + GB, 256, 0, stream>>>(
        xb, wb, u, v, src, dst, cursor, edst);

    const int chunks = (N_NODES + NPB - 1) / NPB;
    gather_slice<<<chunks * SL, 256, 0, stream>>>(
        off, edst, u, v, out, sums, sumsq);

    bn_apply<<<(N_NODES * C_OUT / 4) / 1024, 256, 0, stream>>>(
        out, sums, sumsq, gamma, beta);
}